// Round 7
// baseline (357.367 us; speedup 1.0000x reference)
//
#include <hip/hip_runtime.h>
#include <hip/hip_bf16.h>

#define M_DIM 64
#define K_DIM 4096
#define N_DIM 14336
#define KSPLIT 16
#define KSLICE (K_DIM / KSPLIT)  // 256
#define CHUNKS (KSLICE / 32)     // 8
#define NBLK 56                  // n-blocks of 256 columns (4 waves x 64)

typedef __attribute__((ext_vector_type(8))) short bf16x8;
typedef __attribute__((ext_vector_type(4))) float f32x4;
typedef unsigned short u16;

// ---------------------------------------------------------------------------
// prep: split x (fp32) into bf16 hi/lo, stored in MFMA-A-fragment layout:
// elem idx = (k/8)*(64*8) + m*8 + (k%8).
__global__ void prep_split(const float* __restrict__ x, u16* __restrict__ xh,
                           u16* __restrict__ xl) {
  int tg = blockIdx.x * blockDim.x + threadIdx.x;  // 0..32767
  int kb = tg & 511;
  int m = tg >> 9;
  const float* xp = x + m * K_DIM + kb * 8;
  u16 hs[8], ls[8];
#pragma unroll
  for (int j = 0; j < 8; ++j) {
    float v = xp[j];
    unsigned hv = __float_as_uint(v) & 0xFFFF0000u;  // bf16 truncate (exact)
    float r = v - __uint_as_float(hv);
    hs[j] = (u16)(hv >> 16);
    ls[j] = (u16)(__float_as_uint(r) >> 16);
  }
  int o = kb * (M_DIM * 8) + m * 8;
  *(uint4*)(xh + o) = *(uint4*)hs;
  *(uint4*)(xl + o) = *(uint4*)ls;
}

__global__ void rowsum_k(const float* __restrict__ x, float* __restrict__ rs) {
  int m = blockIdx.x;
  int t = threadIdx.x;
  float s = 0.f;
  for (int k = t; k < K_DIM; k += 256) s += x[m * K_DIM + k];
#pragma unroll
  for (int off = 32; off > 0; off >>= 1) s += __shfl_down(s, off, 64);
  __shared__ float red[4];
  if ((t & 63) == 0) red[t >> 6] = s;
  __syncthreads();
  if (t == 0) rs[m] = red[0] + red[1] + red[2] + red[3];
}

// ---------------------------------------------------------------------------
// Streaming GEMM v4. R6 post-mortem: A-frag GLOBAL loads at the top of each
// COMPUTE were the youngest vmem ops — MFMA's wait on them forced vmcnt(0),
// draining both prefetched W chunks every iteration (vmcnt is in-order).
// Fix: A staged to LDS once (single barrier, before any W prefetch); in-loop
// A reads are ds_read_b128 (lgkmcnt), leaving the cvt's vmcnt(64) as the only
// vmem wait -> prefetch depth 2 is actually honored.
__global__ __launch_bounds__(256) void wqmm(
    const int* __restrict__ W, const u16* __restrict__ xh,
    const u16* __restrict__ xl, float* __restrict__ partial) {
  __shared__ __align__(16) u16 ash[2][KSLICE / 8][M_DIM * 8];  // 64 KB

  const int t = threadIdx.x;
  const int lane = t & 63;
  const int wv = t >> 6;
  const int quad = lane >> 4;
  const int lnk = lane & 15;
  const int ks = blockIdx.x / NBLK;             // 0..15 (uniform per block)
  const int nt = (blockIdx.x % NBLK) * 4 + wv;  // 0..223
  const int k0 = ks * KSLICE;
  const int nbase = nt * 64;

  // stage A slice (linear copy; slice = elems [ks*32*512, +16384) per array)
  {
    const uint4* srch = (const uint4*)(xh + (size_t)ks * 32 * 512);
    const uint4* srcl = (const uint4*)(xl + (size_t)ks * 32 * 512);
    uint4* dsth = (uint4*)&ash[0][0][0];
    uint4* dstl = (uint4*)&ash[1][0][0];
#pragma unroll
    for (int i = 0; i < 8; ++i) {  // 32KB / 16B / 256thr = 8
      dsth[t + i * 256] = srch[t + i * 256];
      dstl[t + i * 256] = srcl[t + i * 256];
    }
  }
  __syncthreads();  // drains staging vmem; W prefetch starts after

  // loop-invariant per-lane dword offsets (encourage saddr-form loads)
  int laneoff[4];
#pragma unroll
  for (int f = 0; f < 4; ++f)
    laneoff[f] = quad * 8 * N_DIM + nbase + lnk + f * 16;

  f32x4 acc[4][4] = {};  // [m-tile][n-frag]
  int raw[3][4][8];      // [buf][n-frag][k-row] — literal indices only

#define LOADW(CC, BUF)                                                \
  do {                                                                \
    _Pragma("unroll") for (int j = 0; j < 8; ++j) {                   \
      const int* bj = W + (size_t)(k0 + (CC) * 32 + j) * N_DIM;       \
      _Pragma("unroll") for (int f = 0; f < 4; ++f)                   \
          raw[BUF][f][j] = bj[laneoff[f]];                            \
    }                                                                 \
  } while (0)

#define COMPUTE(CC, BUF)                                                     \
  do {                                                                       \
    bf16x8 ah[4], al[4];                                                     \
    _Pragma("unroll") for (int mt = 0; mt < 4; ++mt) {                       \
      ah[mt] = *(const bf16x8*)&ash[0][(CC)*4 + quad][(mt * 16 + lnk) * 8];  \
      al[mt] = *(const bf16x8*)&ash[1][(CC)*4 + quad][(mt * 16 + lnk) * 8];  \
    }                                                                        \
    bf16x8 bfr[4];                                                           \
    _Pragma("unroll") for (int f = 0; f < 4; ++f) {                          \
      union {                                                                \
        int i4[4];                                                           \
        bf16x8 v;                                                            \
      } u;                                                                   \
      _Pragma("unroll") for (int wd = 0; wd < 4; ++wd) {                     \
        unsigned lo = __float_as_uint((float)raw[BUF][f][2 * wd]);           \
        unsigned hi = __float_as_uint((float)raw[BUF][f][2 * wd + 1]);       \
        u.i4[wd] = (int)((lo >> 16) | (hi & 0xFFFF0000u)); /* exact */       \
      }                                                                      \
      bfr[f] = u.v;                                                          \
    }                                                                        \
    _Pragma("unroll") for (int mt = 0; mt < 4; ++mt) {                       \
      _Pragma("unroll") for (int f = 0; f < 4; ++f) {                        \
        acc[mt][f] = __builtin_amdgcn_mfma_f32_16x16x32_bf16(                \
            ah[mt], bfr[f], acc[mt][f], 0, 0, 0);                            \
        acc[mt][f] = __builtin_amdgcn_mfma_f32_16x16x32_bf16(                \
            al[mt], bfr[f], acc[mt][f], 0, 0, 0);                            \
      }                                                                      \
    }                                                                        \
  } while (0)

  // software pipeline, prefetch depth 2, buffers cycle mod 3 (CHUNKS == 8)
  LOADW(0, 0);
  LOADW(1, 1);
  LOADW(2, 2);
  COMPUTE(0, 0);
  LOADW(3, 0);
  COMPUTE(1, 1);
  LOADW(4, 1);
  COMPUTE(2, 2);
  LOADW(5, 2);
  COMPUTE(3, 0);
  LOADW(6, 0);
  COMPUTE(4, 1);
  LOADW(7, 1);
  COMPUTE(5, 2);
  COMPUTE(6, 0);
  COMPUTE(7, 1);
#undef LOADW
#undef COMPUTE

  // epilogue: plain coalesced stores to this k-slice's private partial buffer
  float* pp = partial + (size_t)ks * (M_DIM * N_DIM);
#pragma unroll
  for (int f = 0; f < 4; ++f) {
    int n = nbase + f * 16 + lnk;
#pragma unroll
    for (int mt = 0; mt < 4; ++mt) {
#pragma unroll
      for (int r = 0; r < 4; ++r) {
        int m = mt * 16 + quad * 4 + r;  // C/D: col=lane&15, row=quad*4+reg
        pp[(size_t)m * N_DIM + n] = acc[mt][f][r];
      }
    }
  }
}

// ---------------------------------------------------------------------------
// reduce: out = scale * sum_ks(partial) + scale*offset*rowsum[m] + bias
__global__ __launch_bounds__(256) void reduce_k(
    const float* __restrict__ partial, const float* __restrict__ rowsum,
    const float* __restrict__ scale, const float* __restrict__ offset,
    const float* __restrict__ bias, float* __restrict__ out) {
  int i = blockIdx.x * blockDim.x + threadIdx.x;  // over M*N/4 float4s
  int m = i / (N_DIM / 4);
  int nc = i - m * (N_DIM / 4);

  float4 a = ((const float4*)partial)[i];
#pragma unroll
  for (int ks = 1; ks < KSPLIT; ++ks) {
    float4 p = ((const float4*)(partial + (size_t)ks * (M_DIM * N_DIM)))[i];
    a.x += p.x; a.y += p.y; a.z += p.z; a.w += p.w;
  }
  float4 s = ((const float4*)scale)[nc];
  float4 o = ((const float4*)offset)[nc];
  float4 b = ((const float4*)bias)[nc];
  float rs = rowsum[m];
  float4 r;
  r.x = a.x * s.x + s.x * o.x * rs + b.x;
  r.y = a.y * s.y + s.y * o.y * rs + b.y;
  r.z = a.z * s.z + s.z * o.z * rs + b.z;
  r.w = a.w * s.w + s.w * o.w * rs + b.w;
  ((float4*)out)[i] = r;
}

extern "C" void kernel_launch(void* const* d_in, const int* in_sizes, int n_in,
                              void* d_out, int out_size, void* d_ws,
                              size_t ws_size, hipStream_t stream) {
  const float* x = (const float*)d_in[0];
  const int* W = (const int*)d_in[1];
  const float* scale = (const float*)d_in[2];
  const float* offset = (const float*)d_in[3];
  const float* bias = (const float*)d_in[4];
  float* out = (float*)d_out;

  char* wsb = (char*)d_ws;
  float* partial = (float*)wsb;  // KSPLIT * M*N fp32 = 58,720,256 B
  u16* xh = (u16*)(wsb + (size_t)KSPLIT * M_DIM * N_DIM * 4);
  u16* xl = xh + (size_t)M_DIM * K_DIM;
  float* rowsum = (float*)(xl + (size_t)M_DIM * K_DIM);

  prep_split<<<128, 256, 0, stream>>>(x, xh, xl);
  rowsum_k<<<64, 256, 0, stream>>>(x, rowsum);
  wqmm<<<NBLK * KSPLIT, 256, 0, stream>>>(W, xh, xl, partial);
  reduce_k<<<M_DIM * N_DIM / 4 / 256, 256, 0, stream>>>(
      partial, rowsum, scale, offset, bias, out);
}

// Round 8
// 343.455 us; speedup vs baseline: 1.0405x; 1.0405x over previous
//
#include <hip/hip_runtime.h>
#include <hip/hip_bf16.h>

#define M_DIM 64
#define K_DIM 4096
#define N_DIM 14336
#define NBLKS 224       // one block per 64 n-cols
#define KW 1024         // k-range per wave (4 waves cover K=4096)
#define WCHUNKS 32      // 32-k chunks per wave

typedef __attribute__((ext_vector_type(8))) short bf16x8;
typedef __attribute__((ext_vector_type(4))) float f32x4;
typedef unsigned short u16;

// ---------------------------------------------------------------------------
// prep: split x (fp32) into bf16 hi/lo, stored in MFMA-A-fragment layout:
// elem idx = (k/8)*(64*8) + m*8 + (k%8).
__global__ void prep_split(const float* __restrict__ x, u16* __restrict__ xh,
                           u16* __restrict__ xl) {
  int tg = blockIdx.x * blockDim.x + threadIdx.x;  // 0..32767
  int kb = tg & 511;
  int m = tg >> 9;
  const float* xp = x + m * K_DIM + kb * 8;
  u16 hs[8], ls[8];
#pragma unroll
  for (int j = 0; j < 8; ++j) {
    float v = xp[j];
    unsigned hv = __float_as_uint(v) & 0xFFFF0000u;  // bf16 truncate (exact)
    float r = v - __uint_as_float(hv);
    hs[j] = (u16)(hv >> 16);
    ls[j] = (u16)(__float_as_uint(r) >> 16);
  }
  int o = kb * (M_DIM * 8) + m * 8;
  *(uint4*)(xh + o) = *(uint4*)hs;
  *(uint4*)(xl + o) = *(uint4*)ls;
}

__global__ void rowsum_k(const float* __restrict__ x, float* __restrict__ rs) {
  int m = blockIdx.x;
  int t = threadIdx.x;
  float s = 0.f;
  for (int k = t; k < K_DIM; k += 256) s += x[m * K_DIM + k];
#pragma unroll
  for (int off = 32; off > 0; off >>= 1) s += __shfl_down(s, off, 64);
  __shared__ float red[4];
  if ((t & 63) == 0) red[t >> 6] = s;
  __syncthreads();
  if (t == 0) rs[m] = red[0] + red[1] + red[2] + red[3];
}

// ---------------------------------------------------------------------------
// Streaming GEMM v5 — zero auxiliary global traffic (R7 post-mortem: deltas
// track total memory traffic; KSPLIT partials cost 117 MB round-trip). 224
// blocks, one per 64 n-cols; block covers FULL K: wave wv owns k in
// [wv*1024, +1024). Intra-block k-reduction via LDS + fused affine epilogue
// -> direct store to out. Traffic = W 235 MB + A (L2-hot) + out 3.7 MB.
// W depth-1 register double-buffer (chunk consumption ~3200cyc >> 900cyc
// latency); A-frag global loads issued one chunk ahead (L2-resident, 1 MB).
__global__ __launch_bounds__(256, 1) void wqmm(
    const int* __restrict__ W, const u16* __restrict__ xh,
    const u16* __restrict__ xl, const float* __restrict__ rowsum,
    const float* __restrict__ scale, const float* __restrict__ offset,
    const float* __restrict__ bias, float* __restrict__ out) {
  __shared__ __align__(16) float red[4][64][66];  // 67.6 KB, 2-way max

  const int t = threadIdx.x;
  const int lane = t & 63;
  const int wv = t >> 6;       // k-quarter
  const int quad = lane >> 4;
  const int lnk = lane & 15;
  const int nbase = blockIdx.x * 64;
  const int k0 = wv * KW;

  // loop-invariant per-lane dword offsets into W
  int laneoff[4];
#pragma unroll
  for (int f = 0; f < 4; ++f)
    laneoff[f] = quad * 8 * N_DIM + nbase + lnk + f * 16;

  const u16* xhp = xh + (size_t)(wv * 128 + quad) * 512 + lnk * 8;
  const u16* xlp = xl + (size_t)(wv * 128 + quad) * 512 + lnk * 8;

  f32x4 acc[4][4] = {};       // [m-tile][n-frag]
  int raw[2][4][8];           // W double buffer (literal indices only)
  bf16x8 abh[2][4], abl[2][4];  // A double buffer

#define LOADW(CC, BUF)                                            \
  do {                                                            \
    _Pragma("unroll") for (int j = 0; j < 8; ++j) {               \
      const int* bj = W + (size_t)(k0 + (CC) * 32 + j) * N_DIM;   \
      _Pragma("unroll") for (int f = 0; f < 4; ++f)               \
          raw[BUF][f][j] = bj[laneoff[f]];                        \
    }                                                             \
  } while (0)

#define LOADA(CC, BUF)                                            \
  do {                                                            \
    const u16* ahc = xhp + (CC) * 2048;                           \
    const u16* alc = xlp + (CC) * 2048;                           \
    _Pragma("unroll") for (int mt = 0; mt < 4; ++mt) {            \
      abh[BUF][mt] = *(const bf16x8*)(ahc + mt * 128);            \
      abl[BUF][mt] = *(const bf16x8*)(alc + mt * 128);            \
    }                                                             \
  } while (0)

#define COMPUTE(CC, BUF)                                                     \
  do {                                                                       \
    bf16x8 bfr[4];                                                           \
    _Pragma("unroll") for (int f = 0; f < 4; ++f) {                          \
      union {                                                                \
        int i4[4];                                                           \
        bf16x8 v;                                                            \
      } u;                                                                   \
      _Pragma("unroll") for (int wd = 0; wd < 4; ++wd) {                     \
        unsigned lo = __float_as_uint((float)raw[BUF][f][2 * wd]);           \
        unsigned hi = __float_as_uint((float)raw[BUF][f][2 * wd + 1]);       \
        u.i4[wd] = (int)((lo >> 16) | (hi & 0xFFFF0000u)); /* exact */       \
      }                                                                      \
      bfr[f] = u.v;                                                          \
    }                                                                        \
    _Pragma("unroll") for (int mt = 0; mt < 4; ++mt) {                       \
      _Pragma("unroll") for (int f = 0; f < 4; ++f) {                        \
        acc[mt][f] = __builtin_amdgcn_mfma_f32_16x16x32_bf16(                \
            abh[BUF][mt], bfr[f], acc[mt][f], 0, 0, 0);                      \
        acc[mt][f] = __builtin_amdgcn_mfma_f32_16x16x32_bf16(                \
            abl[BUF][mt], bfr[f], acc[mt][f], 0, 0, 0);                      \
      }                                                                      \
    }                                                                        \
  } while (0)

  LOADW(0, 0);
  LOADA(0, 0);
  for (int c = 0; c < WCHUNKS; c += 2) {  // literal buffer indices in body
    LOADW(c + 1, 1);
    LOADA(c + 1, 1);
    COMPUTE(c, 0);
    if (c + 2 < WCHUNKS) {
      LOADW(c + 2, 0);
      LOADA(c + 2, 0);
    }
    COMPUTE(c + 1, 1);
  }
#undef LOADW
#undef LOADA
#undef COMPUTE

  // intra-block k-reduction: each wave deposits its 64x64 tile
#pragma unroll
  for (int f = 0; f < 4; ++f)
#pragma unroll
    for (int mt = 0; mt < 4; ++mt)
#pragma unroll
      for (int r = 0; r < 4; ++r)
        red[wv][mt * 16 + quad * 4 + r][f * 16 + lnk] = acc[mt][f][r];
  __syncthreads();

  // fused epilogue: out = scale*sum + scale*offset*rowsum[m] + bias
#pragma unroll
  for (int i = 0; i < 16; ++i) {
    int idx = t + i * 256;  // linear over 64x64 tile -> coalesced stores
    int m = idx >> 6;
    int nc = idx & 63;
    float s = red[0][m][nc] + red[1][m][nc] + red[2][m][nc] + red[3][m][nc];
    int n = nbase + nc;
    float sc = scale[n];
    out[(size_t)m * N_DIM + n] = s * sc + sc * offset[n] * rowsum[m] + bias[n];
  }
}

extern "C" void kernel_launch(void* const* d_in, const int* in_sizes, int n_in,
                              void* d_out, int out_size, void* d_ws,
                              size_t ws_size, hipStream_t stream) {
  const float* x = (const float*)d_in[0];
  const int* W = (const int*)d_in[1];
  const float* scale = (const float*)d_in[2];
  const float* offset = (const float*)d_in[3];
  const float* bias = (const float*)d_in[4];
  float* out = (float*)d_out;

  char* wsb = (char*)d_ws;
  u16* xh = (u16*)wsb;                          // 512 KB
  u16* xl = xh + (size_t)M_DIM * K_DIM;         // 512 KB
  float* rowsum = (float*)(xl + (size_t)M_DIM * K_DIM);

  prep_split<<<128, 256, 0, stream>>>(x, xh, xl);
  rowsum_k<<<64, 256, 0, stream>>>(x, rowsum);
  wqmm<<<NBLKS, 256, 0, stream>>>(W, xh, xl, rowsum, scale, offset, bias, out);
}